// Round 2
// baseline (325.177 us; speedup 1.0000x reference)
//
#include <hip/hip_runtime.h>
#include <math.h>

#define NCLS 31
#define B 4096
#define D 512
#define N 8192
#define BT 128                    // block super-tile = 128x128 = 2x2 wave-tiles of 64x64
#define NT (N / BT)               // 64 super-tiles per dim
#define NBLK (NT * (NT + 1) / 2)  // 2080 upper-tri super-tiles
#define NSTEP 16                  // K=512 / 32 per MFMA step
#define NPRE 512                  // k_pre blocks (16 rows each)
#define NWAVE_TOT (NBLK * 4)      // wave-level done counter target

// ws float-index layout (memset zeroes first 24576 B = 6144 floats)
#define WS_SUMSQB 0      // 8 bucketed sumsq accumulators
#define WS_NBT    9
#define WS_SL     10
#define WS_CNT    11     // int done-counter (k_main, per-wave)
#define WS_CNT2   12     // int done-counter (k_pre)
#define WS_HIST   16     // 31 ints
#define WS_PRES   47     // unsigned mask
#define WS_CSUM   48     // 31 floats
#define WS_SVAL   80     // 32
#define WS_TVAL   112    // 32 (tval[31] = 0 -> clamp trick for logits tail)
#define WS_ACCB   256    // 64 buckets, stride 16 floats (one line each)
#define WS_COLP   1280   // 8*512 bucketed column-sum partials (ends 5376)
#define WS_SQ     5376   // 8192 row squared norms (fully written by k_pre)
#define WS_XC_BYTES 65536  // Xc: bf16, fragment-tiled [rowblk 512][kblk 16][lane 64][8], 8 MB

typedef __attribute__((ext_vector_type(8))) short bf16x8;
typedef __attribute__((ext_vector_type(4))) float f32x4;
typedef __attribute__((ext_vector_type(8))) unsigned short u16x8;
// 4-byte-aligned float4 for logits rows (stride 31 floats -> not 16B aligned)
typedef __attribute__((ext_vector_type(4), aligned(4))) float f32x4u;

__device__ __forceinline__ unsigned short f2bf(float x) {
  unsigned u = __float_as_uint(x);
  u += 0x7fffu + ((u >> 16) & 1u);  // RNE (inputs finite)
  return (unsigned short)(u >> 16);
}
__device__ __forceinline__ float bf2f(unsigned short b) {
  return __uint_as_float(((unsigned)b) << 16);
}

// k_pre: bf16 convert (fragment-tiled store for k_main's coalesced VGPR loads)
// + row sumsq + colsum + class stats; LAST block finalizes all stats.
// Xc layout: rowblk = row/16 (16 KB each); within: kblk = k/32 (1 KB each);
// within: slot = (granule&3)*16 + (row&15), 16 B per slot. k_main lane l reads
// slot l -> (fg = l>>4, fr = l&15) matches MFMA fragment mapping.
__global__ void k_pre(const float* __restrict__ src, const float* __restrict__ tgt,
                      const int* __restrict__ label, const float* __restrict__ logits,
                      const int* __restrict__ iter_p, float* __restrict__ wsf,
                      unsigned short* __restrict__ Xc) {
  __shared__ float rowbuf[4][512];
  __shared__ float ssq[4];
  __shared__ int lcnt[32];
  __shared__ float lcsum[32];
  __shared__ unsigned lpres;
  __shared__ float red_[4];
  __shared__ int lastblk;
  const int tid = threadIdx.x, w = tid >> 6, lane = tid & 63;
  const int b = blockIdx.x;
  if (tid < 32) { lcnt[tid] = 0; lcsum[tid] = 0.f; }
  if (tid == 0) lpres = 0u;

  float c0acc = 0.f, c1acc = 0.f, ssqacc = 0.f;
  for (int g = 0; g < 4; ++g) {           // 4 row-groups of 4 rows = 16 rows/block
    const int row = (b * 4 + g) * 4 + w;  // = b*16 + g*4 + w  (rowblk == b)
    const float* p = (row < B) ? src + (size_t)row * D : tgt + (size_t)(row - B) * D;
    // lane owns cols [lane*8, lane*8+8)
    float4 a  = ((const float4*)p)[lane * 2];
    float4 bb = ((const float4*)p)[lane * 2 + 1];
    u16x8 hv;
    hv[0] = f2bf(a.x);  hv[1] = f2bf(a.y);  hv[2] = f2bf(a.z);  hv[3] = f2bf(a.w);
    hv[4] = f2bf(bb.x); hv[5] = f2bf(bb.y); hv[6] = f2bf(bb.z); hv[7] = f2bf(bb.w);
    // granule g8 = lane: kblk = lane>>2, fg = lane&3, fr = row&15
    size_t dst = (size_t)(row >> 4) * 8192 + (size_t)(lane >> 2) * 512
               + (size_t)((lane & 3) * 16 + (row & 15)) * 8;
    *(u16x8*)(Xc + dst) = hv;
    float s = a.x*a.x + a.y*a.y + a.z*a.z + a.w*a.w
            + bb.x*bb.x + bb.y*bb.y + bb.z*bb.z + bb.w*bb.w;
    *(float4*)&rowbuf[w][lane * 8]     = a;
    *(float4*)&rowbuf[w][lane * 8 + 4] = bb;
    #pragma unroll
    for (int off = 32; off; off >>= 1) s += __shfl_down(s, off);
    if (lane == 0) { wsf[WS_SQ + row] = s; ssq[w] = s; }
    __syncthreads();
    c0acc += rowbuf[0][tid] + rowbuf[1][tid] + rowbuf[2][tid] + rowbuf[3][tid];
    c1acc += rowbuf[0][tid+256] + rowbuf[1][tid+256] + rowbuf[2][tid+256] + rowbuf[3][tid+256];
    if (tid == 0) ssqacc += ssq[0] + ssq[1] + ssq[2] + ssq[3];
    __syncthreads();
  }
  // class stats for this block's 16 rows
  {
    const int r0 = b * 16;
    if (r0 < B) {
      if (tid < 16) atomicAdd(&lcnt[label[r0 + tid]], 1);
      __syncthreads();
      if (tid < NCLS && lcnt[tid]) atomicAdd((int*)&wsf[WS_HIST] + tid, lcnt[tid]);
    } else {
      if (tid < 16) {
        const float* lp = logits + (size_t)(r0 - B + tid) * NCLS;
        float mx = -1e30f; int am = 0;
        #pragma unroll
        for (int c = 0; c < NCLS; c++) {
          float v = lp[c];
          atomicAdd(&lcsum[c], v);
          if (v > mx) { mx = v; am = c; }  // strict >: first max, matches argmax
        }
        atomicOr(&lpres, 1u << am);
      }
      __syncthreads();
      if (tid < NCLS) atomicAdd(&wsf[WS_CSUM + tid], lcsum[tid]);
      if (tid == 0) atomicOr((unsigned*)&wsf[WS_PRES], lpres);
    }
  }
  // one bucketed atomic set per block
  const int bkt = (b & 7) * 512;
  atomicAdd(&wsf[WS_COLP + bkt + tid], c0acc);
  atomicAdd(&wsf[WS_COLP + bkt + 256 + tid], c1acc);
  if (tid == 0) atomicAdd(&wsf[WS_SUMSQB + (b & 7)], ssqacc);

  // done-counter; last block finalizes stats
  __syncthreads();
  if (tid == 0)
    lastblk = (__hip_atomic_fetch_add((int*)&wsf[WS_CNT2], 1,
               __ATOMIC_RELEASE, __HIP_MEMORY_SCOPE_AGENT) == NPRE - 1);
  __syncthreads();
  if (!lastblk) return;
  __threadfence();  // acquire: see all blocks' atomics/stores
  float cs0 = 0.f, cs1 = 0.f;
  #pragma unroll
  for (int bk = 0; bk < 8; bk++) {
    cs0 += wsf[WS_COLP + bk * 512 + tid];
    cs1 += wsf[WS_COLP + bk * 512 + 256 + tid];
  }
  float v = cs0 * cs0 + cs1 * cs1;
  #pragma unroll
  for (int off = 32; off; off >>= 1) v += __shfl_down(v, off);
  if (lane == 0) red_[w] = v;
  __syncthreads();
  if (tid < 32) {
    // one class per lane (parallel loads), ballot for the mask count
    unsigned presT = *(unsigned*)&wsf[WS_PRES];
    const int c = tid;
    int cnt = (c < NCLS) ? ((int*)&wsf[WS_HIST])[c] : 0;
    float csum = (c < NCLS) ? wsf[WS_CSUM + c] : 0.f;
    bool m = (cnt > 0) && ((presT >> c) & 1u);
    if (csum == 0.f) csum = 100.f;
    wsf[WS_SVAL + c] = m ? 1.f / (float)cnt : 0.f;
    wsf[WS_TVAL + c] = m ? -1.f / csum : 0.f;   // tval[31] stays 0 (clamp trick)
    unsigned long long bal = __ballot(m);
    if (tid == 0) {
      int cm = __popcll(bal);
      float scale = (cm > 0) ? 1.f / (float)cm : 0.f;
      float pp = (float)iter_p[0] / 1000.f;
      float lamb = 2.f / (1.f + __expf(-pp)) - 1.f;
      wsf[WS_SL] = scale * lamb;
      double colnorm2 = (double)red_[0] + red_[1] + red_[2] + red_[3];
      double sumsq = 0.0;
      for (int bk = 0; bk < 8; bk++) sumsq += (double)wsf[WS_SUMSQB + bk];
      double sumL2 = 2.0 * (double)N * sumsq - 2.0 * colnorm2;
      wsf[WS_NBT] = (float)(-((double)N * (double)N - (double)N) / (4.0 * sumL2));
    }
  }
}

// R11: zero-LDS, zero-barrier k_main. R1's counters showed ~90% wave-stall with
// every pipe <28% and L2-miss traffic trivial (82 MB): the 2-phase
// barrier-locked LDS schedule was the ceiling, not any pipe (cf. m233). Each
// wave now owns a private 64x64 tile (block = 2x2 wave-tiles of one 128x128
// super-tile, same L2 footprint as before). Xc is stored fragment-tiled so
// each MFMA operand fragment is ONE fully-coalesced dwordx4/lane load
// global->VGPR; K-loop ping-pongs two frag sets (1-step prefetch, per-wave
// vmcnt by compiler). Gram Q-frags built in-register (no LDS), MFMA
// chain-accumulated (saves 2/3 of the dot VALU). setprio around MFMA
// clusters: waves are independent here (attn-like regime where T5 paid).
__launch_bounds__(256, 3)
__global__ void k_main(const unsigned short* __restrict__ Xc,
                       const int* __restrict__ label, const float* __restrict__ logits,
                       float* __restrict__ wsf, float* __restrict__ out) {
  // triangular super-tile decode: bi <= bj, S(bi) = bi*(129-bi)/2
  int bid = blockIdx.x;
  int bi = (int)(64.5f - sqrtf(64.5f * 64.5f - 2.0f * (float)bid));
  while (bi > 0 && bid < (bi * (129 - bi)) / 2) --bi;
  while (bid >= ((bi + 1) * (128 - bi)) / 2) ++bi;
  int bj = bi + (bid - (bi * (129 - bi)) / 2);

  const int tid = threadIdx.x;
  const int w = tid >> 6, lane = tid & 63;
  const int iw = bi * BT + (w >> 1) * 64;   // wave-tile rows [iw, iw+64)
  const int jw = bj * BT + (w & 1) * 64;    // wave-tile cols [jw, jw+64)
  float mult = (iw == jw) ? 1.f : 2.f;
  if (iw > jw) mult = 0.f;                  // lower-tri duplicate (diag supers, w==2)

  const int fr = lane & 15, fg = lane >> 4;
  float part = 0.f;

  if (mult != 0.f) {
    // ---- K-loop: global->VGPR, ping-pong prefetch, no LDS, no barriers ----
    const unsigned short* pa = Xc + (size_t)(iw >> 4) * 8192 + (size_t)lane * 8;
    const unsigned short* pb = Xc + (size_t)(jw >> 4) * 8192 + (size_t)lane * 8;

    f32x4 acc[4][4];
    #pragma unroll
    for (int mt = 0; mt < 4; mt++)
      #pragma unroll
      for (int nt = 0; nt < 4; nt++) acc[mt][nt] = (f32x4){0.f, 0.f, 0.f, 0.f};

    bf16x8 a0[4], b0[4], a1[4], b1[4];
    #define LDAB(Adst, Bdst, s) do {                                          \
      _Pragma("unroll")                                                       \
      for (int mt = 0; mt < 4; ++mt) {                                        \
        Adst[mt] = *(const bf16x8*)(pa + mt * 8192 + (s) * 512);              \
        Bdst[mt] = *(const bf16x8*)(pb + mt * 8192 + (s) * 512);              \
      }                                                                       \
    } while (0)

    LDAB(a0, b0, 0);
    #pragma unroll
    for (int s = 0; s < NSTEP; s += 2) {
      if (s + 1 < NSTEP) LDAB(a1, b1, s + 1);
      __builtin_amdgcn_s_setprio(1);
      #pragma unroll
      for (int mt = 0; mt < 4; mt++)
        #pragma unroll
        for (int nt = 0; nt < 4; nt++)
          acc[mt][nt] = __builtin_amdgcn_mfma_f32_16x16x32_bf16(
              a0[mt], b0[nt], acc[mt][nt], 0, 0, 0);
      __builtin_amdgcn_s_setprio(0);
      if (s + 2 < NSTEP) LDAB(a0, b0, s + 2);
      __builtin_amdgcn_s_setprio(1);
      #pragma unroll
      for (int mt = 0; mt < 4; mt++)
        #pragma unroll
        for (int nt = 0; nt < 4; nt++)
          acc[mt][nt] = __builtin_amdgcn_mfma_f32_16x16x32_bf16(
              a1[mt], b1[nt], acc[mt][nt], 0, 0, 0);
      __builtin_amdgcn_s_setprio(0);
    }
    #undef LDAB

    // ---- acc -> multi-band Gaussian kernel: t + t^2 + t^4 + t^8 + t^16 ----
    const float nbt = wsf[WS_NBT];
    float sj4[4], si16[4][4];
    #pragma unroll
    for (int nt = 0; nt < 4; nt++) sj4[nt] = wsf[WS_SQ + jw + nt * 16 + fr];
    #pragma unroll
    for (int mt = 0; mt < 4; mt++)
      #pragma unroll
      for (int t = 0; t < 4; t++)
        si16[mt][t] = wsf[WS_SQ + iw + mt * 16 + fg * 4 + t];
    #pragma unroll
    for (int mt = 0; mt < 4; mt++)
      #pragma unroll
      for (int nt = 0; nt < 4; nt++)
        #pragma unroll
        for (int t = 0; t < 4; t++) {
          float d2 = fmaxf(si16[mt][t] + sj4[nt] - 2.f * acc[mt][nt][t], 0.f);
          float e1 = __expf(d2 * nbt);
          float e2 = e1 * e1, e4 = e2 * e2, e8 = e4 * e4, e16 = e8 * e8;
          acc[mt][nt][t] = ((e16 + e8) + (e4 + e2)) + e1;
        }

    // ---- Gram via in-register Q frags (hi/lo split, K=32 classes) ----
    float tv[8];
    #pragma unroll
    for (int j = 0; j < 8; ++j) tv[j] = wsf[WS_TVAL + fg * 8 + j];  // tval[31]=0

    bf16x8 ah[4], al[4], bh[4], bl[4];
    #define BUILDQ(r0, qh, ql) do {                                           \
      const int gr = (r0) + fr;                                               \
      u16x8 h_ = (u16x8){0,0,0,0,0,0,0,0}, l_ = (u16x8){0,0,0,0,0,0,0,0};     \
      if (gr < B) {                                                           \
        const int lab = label[gr];                                            \
        if ((lab >> 3) == fg) {                                               \
          const float sv = wsf[WS_SVAL + lab];                                \
          unsigned short hh = f2bf(sv);                                       \
          h_[lab & 7] = hh;                                                   \
          l_[lab & 7] = f2bf(sv - bf2f(hh));                                  \
        }                                                                     \
      } else {                                                                \
        const float* lp = logits + (size_t)(gr - B) * NCLS;                   \
        const int c0 = fg * 8;                                                \
        f32x4u v0 = *(const f32x4u*)(lp + c0);                                \
        f32x4u v1 = *(const f32x4u*)(lp + c0 + ((fg == 3) ? 3 : 4));          \
        float e_[8];                                                          \
        e_[0] = v0.x; e_[1] = v0.y; e_[2] = v0.z; e_[3] = v0.w;               \
        if (fg == 3) { e_[4] = v1.y; e_[5] = v1.z; e_[6] = v1.w; e_[7] = v1.w; } \
        else         { e_[4] = v1.x; e_[5] = v1.y; e_[6] = v1.z; e_[7] = v1.w; } \
        _Pragma("unroll")                                                     \
        for (int j = 0; j < 8; ++j) {                                         \
          float vq = e_[j] * tv[j];                                           \
          unsigned short hh = f2bf(vq);                                       \
          h_[j] = hh; l_[j] = f2bf(vq - bf2f(hh));                            \
        }                                                                     \
      }                                                                       \
      qh = (bf16x8)h_; ql = (bf16x8)l_;                                       \
    } while (0)

    #pragma unroll
    for (int mt = 0; mt < 4; ++mt) BUILDQ(iw + mt * 16, ah[mt], al[mt]);
    #pragma unroll
    for (int nt = 0; nt < 4; ++nt) BUILDQ(jw + nt * 16, bh[nt], bl[nt]);
    #undef BUILDQ

    __builtin_amdgcn_s_setprio(1);
    #pragma unroll
    for (int mt = 0; mt < 4; mt++)
      #pragma unroll
      for (int nt = 0; nt < 4; nt++) {
        f32x4 g = (f32x4){0.f, 0.f, 0.f, 0.f};
        g = __builtin_amdgcn_mfma_f32_16x16x32_bf16(ah[mt], bl[nt], g, 0, 0, 0);
        g = __builtin_amdgcn_mfma_f32_16x16x32_bf16(al[mt], bh[nt], g, 0, 0, 0);
        g = __builtin_amdgcn_mfma_f32_16x16x32_bf16(ah[mt], bh[nt], g, 0, 0, 0);
        part += acc[mt][nt].x * g.x + acc[mt][nt].y * g.y
              + acc[mt][nt].z * g.z + acc[mt][nt].w * g.w;
      }
    __builtin_amdgcn_s_setprio(0);
    part *= mult;
  }

  // ---- per-wave reduce + bucketed atomic + wave done-counter ----
  #pragma unroll
  for (int off = 32; off; off >>= 1) part += __shfl_down(part, off);
  int old = 0;
  if (lane == 0) {
    atomicAdd(&wsf[WS_ACCB + ((bid * 4 + w) & 63) * 16], part);
    old = __hip_atomic_fetch_add((int*)&wsf[WS_CNT], 1,
                                 __ATOMIC_RELEASE, __HIP_MEMORY_SCOPE_AGENT);
  }
  old = __shfl(old, 0);
  if (old == NWAVE_TOT - 1) {
    __builtin_amdgcn_fence(__ATOMIC_ACQUIRE, "agent");
    float t = __hip_atomic_load(&wsf[WS_ACCB + lane * 16],
                                __ATOMIC_RELAXED, __HIP_MEMORY_SCOPE_AGENT);
    #pragma unroll
    for (int off = 32; off; off >>= 1) t += __shfl_down(t, off);
    if (lane == 0) out[0] = t * wsf[WS_SL];
  }
}

extern "C" void kernel_launch(void* const* d_in, const int* in_sizes, int n_in,
                              void* d_out, int out_size, void* d_ws, size_t ws_size,
                              hipStream_t stream) {
  const float* src    = (const float*)d_in[0];
  const float* tgt    = (const float*)d_in[1];
  const int*   label  = (const int*)d_in[2];
  const float* logits = (const float*)d_in[3];
  const int*   iter_p = (const int*)d_in[4];
  float* wsf = (float*)d_ws;
  unsigned short* Xc = (unsigned short*)((char*)d_ws + WS_XC_BYTES);
  float* out = (float*)d_out;

  hipMemsetAsync(d_ws, 0, 24576, stream);   // zero scalars/counters/buckets/stats
  k_pre<<<NPRE, 256, 0, stream>>>(src, tgt, label, logits, iter_p, wsf, Xc);
  k_main<<<NBLK, 256, 0, stream>>>(Xc, label, logits, wsf, out);
}

// Round 3
// 281.697 us; speedup vs baseline: 1.1544x; 1.1544x over previous
//
#include <hip/hip_runtime.h>
#include <math.h>

#define NCLS 31
#define B 4096
#define D 512
#define N 8192
#define BT 256                    // block super-tile = 256x256, 8 waves of 128x64
#define NT2 (N / BT)              // 32 super-tiles per dim
#define NBLK (NT2 * (NT2 + 1) / 2)  // 528 upper-tri super-tiles
#define NKT 16                    // K=512 / 32 per K-tile
#define NPRE 512                  // k_pre blocks (16 rows each)
#define NWAVE_TOT (NBLK * 8)      // wave-level done counter target

// ws float-index layout (memset zeroes first 24576 B = 6144 floats)
#define WS_SUMSQB 0      // 8 bucketed sumsq accumulators
#define WS_NBT    9
#define WS_SL     10
#define WS_CNT    11     // int done-counter (k_main, per-wave)
#define WS_CNT2   12     // int done-counter (k_pre)
#define WS_HIST   16     // 31 ints
#define WS_PRES   47     // unsigned mask
#define WS_CSUM   48     // 31 floats
#define WS_SVAL   80     // 32
#define WS_TVAL   112    // 32 (tval[31] = 0 -> clamp trick for logits tail)
#define WS_ACCB   256    // 64 buckets, stride 16 floats (one line each)
#define WS_COLP   1280   // 8*512 bucketed column-sum partials (ends 5376)
#define WS_SQ     5376   // 8192 row squared norms (fully written by k_pre)
#define WS_XC_BYTES 65536  // Xc: bf16 [8192][512] row-major, 8 MB

typedef __attribute__((ext_vector_type(8))) short bf16x8;
typedef __attribute__((ext_vector_type(4))) float f32x4;
typedef __attribute__((ext_vector_type(8))) unsigned short u16x8;

__device__ __forceinline__ unsigned short f2bf(float x) {
  unsigned u = __float_as_uint(x);
  u += 0x7fffu + ((u >> 16) & 1u);  // RNE (inputs finite)
  return (unsigned short)(u >> 16);
}
__device__ __forceinline__ float bf2f(unsigned short b) {
  return __uint_as_float(((unsigned)b) << 16);
}

__device__ __forceinline__ void async_lds16(const unsigned short* g, const short* l) {
  __builtin_amdgcn_global_load_lds(
      (const __attribute__((address_space(1))) unsigned int*)g,
      (__attribute__((address_space(3))) unsigned int*)l, 16, 0, 0);
}

// BK=32 tile: rows of 64 B = 4 granules of 16 B; XOR swizzle on (r>>1)&3
__device__ __forceinline__ bf16x8 frag32(const short* buf, int r, int g) {
  int sg = g ^ ((r >> 1) & 3);
  return *(const bf16x8*)(buf + (r * 4 + sg) * 8);
}

// k_pre: R1 version (row-major Xc) — bf16 convert + row sumsq + colsum + class
// stats; LAST block finalizes (lane-parallel class loop).
__global__ void k_pre(const float* __restrict__ src, const float* __restrict__ tgt,
                      const int* __restrict__ label, const float* __restrict__ logits,
                      const int* __restrict__ iter_p, float* __restrict__ wsf,
                      unsigned short* __restrict__ Xc) {
  __shared__ float rowbuf[4][512];
  __shared__ float ssq[4];
  __shared__ int lcnt[32];
  __shared__ float lcsum[32];
  __shared__ unsigned lpres;
  __shared__ float red_[4];
  __shared__ int lastblk;
  const int tid = threadIdx.x, w = tid >> 6, lane = tid & 63;
  const int b = blockIdx.x;
  if (tid < 32) { lcnt[tid] = 0; lcsum[tid] = 0.f; }
  if (tid == 0) lpres = 0u;

  float c0acc = 0.f, c1acc = 0.f, ssqacc = 0.f;
  for (int g = 0; g < 4; ++g) {           // 4 row-groups of 4 rows = 16 rows/block
    const int row = (b * 4 + g) * 4 + w;
    const float* p = (row < B) ? src + (size_t)row * D : tgt + (size_t)(row - B) * D;
    float4 a = ((const float4*)p)[lane], bb = ((const float4*)p)[lane + 64];
    ushort4 ha, hb;
    ha.x = f2bf(a.x); ha.y = f2bf(a.y); ha.z = f2bf(a.z); ha.w = f2bf(a.w);
    hb.x = f2bf(bb.x); hb.y = f2bf(bb.y); hb.z = f2bf(bb.z); hb.w = f2bf(bb.w);
    size_t rb8 = (size_t)row * 512;
    *(ushort4*)(Xc + rb8 + lane * 4)       = ha;   // cols 0..255
    *(ushort4*)(Xc + rb8 + 256 + lane * 4) = hb;   // cols 256..511
    float s = a.x*a.x + a.y*a.y + a.z*a.z + a.w*a.w
            + bb.x*bb.x + bb.y*bb.y + bb.z*bb.z + bb.w*bb.w;
    *(float4*)&rowbuf[w][lane * 4] = a;
    *(float4*)&rowbuf[w][256 + lane * 4] = bb;
    #pragma unroll
    for (int off = 32; off; off >>= 1) s += __shfl_down(s, off);
    if (lane == 0) { wsf[WS_SQ + row] = s; ssq[w] = s; }
    __syncthreads();
    c0acc += rowbuf[0][tid] + rowbuf[1][tid] + rowbuf[2][tid] + rowbuf[3][tid];
    c1acc += rowbuf[0][tid+256] + rowbuf[1][tid+256] + rowbuf[2][tid+256] + rowbuf[3][tid+256];
    if (tid == 0) ssqacc += ssq[0] + ssq[1] + ssq[2] + ssq[3];
    __syncthreads();
  }
  // class stats for this block's 16 rows
  {
    const int r0 = b * 16;
    if (r0 < B) {
      if (tid < 16) atomicAdd(&lcnt[label[r0 + tid]], 1);
      __syncthreads();
      if (tid < NCLS && lcnt[tid]) atomicAdd((int*)&wsf[WS_HIST] + tid, lcnt[tid]);
    } else {
      if (tid < 16) {
        const float* lp = logits + (size_t)(r0 - B + tid) * NCLS;
        float mx = -1e30f; int am = 0;
        #pragma unroll
        for (int c = 0; c < NCLS; c++) {
          float v = lp[c];
          atomicAdd(&lcsum[c], v);
          if (v > mx) { mx = v; am = c; }  // strict >: first max, matches argmax
        }
        atomicOr(&lpres, 1u << am);
      }
      __syncthreads();
      if (tid < NCLS) atomicAdd(&wsf[WS_CSUM + tid], lcsum[tid]);
      if (tid == 0) atomicOr((unsigned*)&wsf[WS_PRES], lpres);
    }
  }
  // one bucketed atomic set per block
  const int bkt = (b & 7) * 512;
  atomicAdd(&wsf[WS_COLP + bkt + tid], c0acc);
  atomicAdd(&wsf[WS_COLP + bkt + 256 + tid], c1acc);
  if (tid == 0) atomicAdd(&wsf[WS_SUMSQB + (b & 7)], ssqacc);

  // done-counter; last block finalizes stats
  __syncthreads();
  if (tid == 0)
    lastblk = (__hip_atomic_fetch_add((int*)&wsf[WS_CNT2], 1,
               __ATOMIC_RELEASE, __HIP_MEMORY_SCOPE_AGENT) == NPRE - 1);
  __syncthreads();
  if (!lastblk) return;
  __threadfence();  // acquire: see all blocks' atomics/stores
  float cs0 = 0.f, cs1 = 0.f;
  #pragma unroll
  for (int bk = 0; bk < 8; bk++) {
    cs0 += wsf[WS_COLP + bk * 512 + tid];
    cs1 += wsf[WS_COLP + bk * 512 + 256 + tid];
  }
  float v = cs0 * cs0 + cs1 * cs1;
  #pragma unroll
  for (int off = 32; off; off >>= 1) v += __shfl_down(v, off);
  if (lane == 0) red_[w] = v;
  __syncthreads();
  if (tid < 32) {
    unsigned presT = *(unsigned*)&wsf[WS_PRES];
    const int c = tid;
    int cnt = (c < NCLS) ? ((int*)&wsf[WS_HIST])[c] : 0;
    float csum = (c < NCLS) ? wsf[WS_CSUM + c] : 0.f;
    bool m = (cnt > 0) && ((presT >> c) & 1u);
    if (csum == 0.f) csum = 100.f;
    wsf[WS_SVAL + c] = m ? 1.f / (float)cnt : 0.f;
    wsf[WS_TVAL + c] = m ? -1.f / csum : 0.f;   // tval[31] stays 0
    unsigned long long bal = __ballot(m);
    if (tid == 0) {
      int cm = __popcll(bal);
      float scale = (cm > 0) ? 1.f / (float)cm : 0.f;
      float pp = (float)iter_p[0] / 1000.f;
      float lamb = 2.f / (1.f + __expf(-pp)) - 1.f;
      wsf[WS_SL] = scale * lamb;
      double colnorm2 = (double)red_[0] + red_[1] + red_[2] + red_[3];
      double sumsq = 0.0;
      for (int bk = 0; bk < 8; bk++) sumsq += (double)wsf[WS_SUMSQB + bk];
      double sumL2 = 2.0 * (double)N * sumsq - 2.0 * colnorm2;
      wsf[WS_NBT] = (float)(-((double)N * (double)N - (double)N) / (4.0 * sumL2));
    }
  }
}

// R12: 256x256 super-tile, 8 waves (2Mx4N, per-wave 128x64), BK=32,
// double-buffered 64 KB LDS, 2 phases per K-tile (T3-style interleave),
// vmcnt(0) only at tile boundaries where awaited loads are >=2 phases old
// (T4: never wait on fresh loads). Q-frags in-register with STATIC indexing
// (R2 post-mortem: runtime ext_vector index -> scratch, WRITE_SIZE 10.8 MB).
// __launch_bounds__(512,2): 2 waves/SIMD -> 256 VGPR cap, 1 block/CU.
__launch_bounds__(512, 2)
__global__ void k_main(const unsigned short* __restrict__ Xc,
                       const int* __restrict__ label, const float* __restrict__ logits,
                       float* __restrict__ wsf, float* __restrict__ out) {
  __shared__ __align__(16) short tA[2][BT * 32];   // 2 x 16 KB
  __shared__ __align__(16) short tB[2][BT * 32];   // 2 x 16 KB  (total 64 KB)

  // triangular super-tile decode: bi <= bj, S(bi) = bi*(65-bi)/2
  int bid = blockIdx.x;
  int bi = (int)(32.5f - sqrtf(32.5f * 32.5f - 2.0f * (float)bid));
  while (bi > 0 && bid < (bi * (65 - bi)) / 2) --bi;
  while (bid >= ((bi + 1) * (64 - bi)) / 2) ++bi;
  int bj = bi + (bid - (bi * (65 - bi)) / 2);
  const int i0 = bi * BT, j0 = bj * BT;
  const float mult = (bi == bj) ? 1.f : 2.f;   // diag supers counted once, full square

  const int tid = threadIdx.x;
  const int w = tid >> 6, lane = tid & 63;
  const int wr = w >> 2, wc = w & 3;            // wave tile: rows wr*128, cols wc*64
  const int fr = lane & 15, fg = lane >> 4;
  // staging: each inst covers 16 rows x 64 B; lane -> (r_local, swizzled granule)
  const int s_r  = lane >> 2;                   // r_local 0..15
  const int s_g  = (lane & 3) ^ ((s_r >> 1) & 3);

  // stage K-tile `t` into buffer `bf`: wave w covers row-groups {2w, 2w+1} of A and B
  #define ISSUE(t, bf) do {                                                    \
    const int off = (t) * 32;                                                  \
    _Pragma("unroll")                                                          \
    for (int q = 0; q < 2; ++q) {                                              \
      const int grp = w * 2 + q;              /* 0..15, 16 rows each */        \
      const int rl = grp * 16 + s_r;                                           \
      async_lds16(Xc + (size_t)(i0 + rl) * 512 + off + s_g * 8,                \
                  &tA[bf][grp * 512]);                                         \
      async_lds16(Xc + (size_t)(j0 + rl) * 512 + off + s_g * 8,                \
                  &tB[bf][grp * 512]);                                         \
    }                                                                          \
  } while (0)

  f32x4 acc[8][4];
  #pragma unroll
  for (int m = 0; m < 8; m++)
    #pragma unroll
    for (int n = 0; n < 4; n++) acc[m][n] = (f32x4){0.f, 0.f, 0.f, 0.f};

  ISSUE(0, 0);

  #pragma unroll 2
  for (int t = 0; t < NKT; ++t) {
    const int cur = t & 1;
    // ---- phase 0: frags mt0-3 + all B; stage next tile; 16 MFMA ----
    asm volatile("s_waitcnt vmcnt(0)" ::: "memory");  // tile t's stages (1 tile old)
    __builtin_amdgcn_s_barrier();
    __builtin_amdgcn_sched_barrier(0);
    bf16x8 af[4], bfr[4];
    #pragma unroll
    for (int mt = 0; mt < 4; mt++)
      af[mt] = frag32(tA[cur], wr * 128 + mt * 16 + fr, fg);
    #pragma unroll
    for (int nt = 0; nt < 4; nt++)
      bfr[nt] = frag32(tB[cur], wc * 64 + nt * 16 + fr, fg);
    if (t + 1 < NKT) ISSUE(t + 1, cur ^ 1);   // buf cur^1: all reads done pre-barrier
    asm volatile("s_waitcnt lgkmcnt(0)" ::: "memory");
    __builtin_amdgcn_sched_barrier(0);
    __builtin_amdgcn_s_setprio(1);
    #pragma unroll
    for (int mt = 0; mt < 4; mt++)
      #pragma unroll
      for (int nt = 0; nt < 4; nt++)
        acc[mt][nt] = __builtin_amdgcn_mfma_f32_16x16x32_bf16(
            af[mt], bfr[nt], acc[mt][nt], 0, 0, 0);
    __builtin_amdgcn_s_setprio(0);
    // ---- phase 1: frags mt4-7 (B reused); 16 MFMA ----
    __builtin_amdgcn_s_barrier();
    __builtin_amdgcn_sched_barrier(0);
    #pragma unroll
    for (int mt = 0; mt < 4; mt++)
      af[mt] = frag32(tA[cur], wr * 128 + 64 + mt * 16 + fr, fg);
    asm volatile("s_waitcnt lgkmcnt(0)" ::: "memory");
    __builtin_amdgcn_sched_barrier(0);
    __builtin_amdgcn_s_setprio(1);
    #pragma unroll
    for (int mt = 0; mt < 4; mt++)
      #pragma unroll
      for (int nt = 0; nt < 4; nt++)
        acc[4 + mt][nt] = __builtin_amdgcn_mfma_f32_16x16x32_bf16(
            af[mt], bfr[nt], acc[4 + mt][nt], 0, 0, 0);
    __builtin_amdgcn_s_setprio(0);
  }
  #undef ISSUE

  // ---- epilogue: exp-bands + in-register Gram + dot (no LDS, no barriers) ----
  const float nbt = wsf[WS_NBT];
  float sj4[4];
  #pragma unroll
  for (int nt = 0; nt < 4; nt++)
    sj4[nt] = wsf[WS_SQ + j0 + wc * 64 + nt * 16 + fr];

  // Q fragment build, static-indexed (rule #20)
  #define BUILDQ(gr_, qh_, ql_) do {                                           \
    const int gr = (gr_);                                                      \
    u16x8 h_ = (u16x8){0,0,0,0,0,0,0,0}, l_ = (u16x8){0,0,0,0,0,0,0,0};        \
    if (gr < B) {                                                              \
      const int lab = label[gr];                                               \
      const float sv = wsf[WS_SVAL + lab];                                     \
      const unsigned short hh = f2bf(sv);                                      \
      const unsigned short ll = f2bf(sv - bf2f(hh));                           \
      const int rel = lab - fg * 8;                                            \
      _Pragma("unroll")                                                        \
      for (int j = 0; j < 8; ++j) {                                            \
        h_[j] = (rel == j) ? hh : (unsigned short)0;                           \
        l_[j] = (rel == j) ? ll : (unsigned short)0;                           \
      }                                                                        \
    } else {                                                                   \
      const float* lp = logits + (size_t)(gr - B) * NCLS;                      \
      _Pragma("unroll")                                                        \
      for (int j = 0; j < 8; ++j) {                                            \
        int cc = fg * 8 + j;                                                   \
        float tv = wsf[WS_TVAL + cc];    /* tval[31] = 0 */                    \
        if (cc > 30) cc = 30;            /* avoid OOB read; tv=0 kills it */   \
        float vq = lp[cc] * tv;                                                \
        unsigned short hh = f2bf(vq);                                          \
        h_[j] = hh; l_[j] = f2bf(vq - bf2f(hh));                               \
      }                                                                        \
    }                                                                          \
    qh_ = (bf16x8)h_; ql_ = (bf16x8)l_;                                        \
  } while (0)

  bf16x8 bh[4], bl[4];
  #pragma unroll
  for (int nt = 0; nt < 4; ++nt)
    BUILDQ(j0 + wc * 64 + nt * 16 + fr, bh[nt], bl[nt]);

  float part = 0.f;
  #pragma unroll
  for (int m = 0; m < 8; ++m) {
    float si[4];
    #pragma unroll
    for (int q = 0; q < 4; ++q)
      si[q] = wsf[WS_SQ + i0 + wr * 128 + m * 16 + fg * 4 + q];
    bf16x8 ah, al;
    BUILDQ(i0 + wr * 128 + m * 16 + fr, ah, al);
    #pragma unroll
    for (int nt = 0; nt < 4; ++nt) {
      f32x4 kv;
      #pragma unroll
      for (int q = 0; q < 4; ++q) {
        float d2 = fmaxf(si[q] + sj4[nt] - 2.f * acc[m][nt][q], 0.f);
        float e1 = __expf(d2 * nbt);
        float e2 = e1 * e1, e4 = e2 * e2, e8 = e4 * e4, e16 = e8 * e8;
        kv[q] = ((e16 + e8) + (e4 + e2)) + e1;
      }
      f32x4 g = (f32x4){0.f, 0.f, 0.f, 0.f};
      g = __builtin_amdgcn_mfma_f32_16x16x32_bf16(ah, bl[nt], g, 0, 0, 0);
      g = __builtin_amdgcn_mfma_f32_16x16x32_bf16(al, bh[nt], g, 0, 0, 0);
      g = __builtin_amdgcn_mfma_f32_16x16x32_bf16(ah, bh[nt], g, 0, 0, 0);
      part += kv.x * g.x + kv.y * g.y + kv.z * g.z + kv.w * g.w;
    }
  }
  #undef BUILDQ
  part *= mult;

  // ---- per-wave reduce + bucketed atomic + wave done-counter ----
  #pragma unroll
  for (int off = 32; off; off >>= 1) part += __shfl_down(part, off);
  int old = 0;
  if (lane == 0) {
    atomicAdd(&wsf[WS_ACCB + ((bid * 8 + w) & 63) * 16], part);
    old = __hip_atomic_fetch_add((int*)&wsf[WS_CNT], 1,
                                 __ATOMIC_RELEASE, __HIP_MEMORY_SCOPE_AGENT);
  }
  old = __shfl(old, 0);
  if (old == NWAVE_TOT - 1) {
    __builtin_amdgcn_fence(__ATOMIC_ACQUIRE, "agent");
    float tsum = __hip_atomic_load(&wsf[WS_ACCB + lane * 16],
                                   __ATOMIC_RELAXED, __HIP_MEMORY_SCOPE_AGENT);
    #pragma unroll
    for (int off = 32; off; off >>= 1) tsum += __shfl_down(tsum, off);
    if (lane == 0) out[0] = tsum * wsf[WS_SL];
  }
}

extern "C" void kernel_launch(void* const* d_in, const int* in_sizes, int n_in,
                              void* d_out, int out_size, void* d_ws, size_t ws_size,
                              hipStream_t stream) {
  const float* src    = (const float*)d_in[0];
  const float* tgt    = (const float*)d_in[1];
  const int*   label  = (const int*)d_in[2];
  const float* logits = (const float*)d_in[3];
  const int*   iter_p = (const int*)d_in[4];
  float* wsf = (float*)d_ws;
  unsigned short* Xc = (unsigned short*)((char*)d_ws + WS_XC_BYTES);
  float* out = (float*)d_out;

  hipMemsetAsync(d_ws, 0, 24576, stream);   // zero scalars/counters/buckets/stats
  k_pre<<<NPRE, 256, 0, stream>>>(src, tgt, label, logits, iter_p, wsf, Xc);
  k_main<<<NBLK, 512, 0, stream>>>(Xc, label, logits, wsf, out);
}

// Round 4
// 193.894 us; speedup vs baseline: 1.6771x; 1.4528x over previous
//
#include <hip/hip_runtime.h>
#include <math.h>

#define NCLS 31
#define B 4096
#define D 512
#define N 8192
#define BT 128
#define NT (N / BT)               // 64 tiles per dim
#define NBLK (NT * (NT + 1) / 2)  // 2080 upper-tri tiles
#define BK32 32                   // bf16 K-chunk per iteration (triple-buffered)
#define NITER 16                  // K=512: pure-bf16 X dot (error ~5e-7 << 1.2e-4 thr)
#define NPRE 1024                 // k_pre blocks (8 rows each)

// ws float-index layout (memset zeroes first 24576 B = 6144 floats)
#define WS_SUMSQB 0      // 8 bucketed sumsq accumulators
#define WS_NBT    9
#define WS_SL     10
#define WS_CNT    11     // int done-counter (k_main)
#define WS_CNT2   12     // int done-counter (k_pre)
#define WS_HIST   16     // 31 ints
#define WS_PRES   47     // unsigned mask
#define WS_CSUM   48     // 31 floats
#define WS_SVAL   80     // 32
#define WS_TVAL   112    // 32
#define WS_ACCB   256    // 64 buckets, stride 16 floats (one line each)
#define WS_COLP   1280   // 8*512 bucketed column-sum partials (ends 5376)
#define WS_SQ     5376   // 8192 row squared norms (fully written by k_pre)
#define WS_XC_BYTES 65536  // Xc: bf16 [8192][512] row-major, 8 MB

typedef __attribute__((ext_vector_type(8))) short bf16x8;
typedef __attribute__((ext_vector_type(4))) float f32x4;
typedef __attribute__((ext_vector_type(8))) unsigned short u16x8;

__device__ __forceinline__ unsigned short f2bf(float x) {
  unsigned u = __float_as_uint(x);
  u += 0x7fffu + ((u >> 16) & 1u);  // RNE (inputs finite)
  return (unsigned short)(u >> 16);
}
__device__ __forceinline__ float bf2f(unsigned short b) {
  return __uint_as_float(((unsigned)b) << 16);
}

__device__ __forceinline__ void async_lds16(const unsigned short* g, const short* l) {
  __builtin_amdgcn_global_load_lds(
      (const __attribute__((address_space(1))) unsigned int*)g,
      (__attribute__((address_space(3))) unsigned int*)l, 16, 0, 0);
}

// BK=32 tile: rows of 64 B = 4 granules of 16 B; XOR swizzle on (r>>1)&3
__device__ __forceinline__ bf16x8 frag32(const short* buf, int r, int g) {
  int sg = g ^ ((r >> 1) & 3);
  return *(const bf16x8*)(buf + (r * 4 + sg) * 8);
}

// R13 k_pre: lean rewrite. 1024 blocks x 8 rows (2 rows/wave). Column sums
// accumulated IN REGISTERS (lane owns cols [lane*4,+4) and [256+lane*4,+4)
// across all its rows) -> no per-row LDS round-trip; barriers 8 -> 2.
// Class stats confined to wave 0 (same-wave LDS ordering, no barrier).
__global__ void k_pre(const float* __restrict__ src, const float* __restrict__ tgt,
                      const int* __restrict__ label, const float* __restrict__ logits,
                      const int* __restrict__ iter_p, float* __restrict__ wsf,
                      unsigned short* __restrict__ Xc) {
  __shared__ __align__(16) float colbuf[4][512];
  __shared__ int lcnt[32];
  __shared__ float lcsum[32];
  __shared__ unsigned lpres;
  __shared__ float red_[4];
  __shared__ int lastblk;
  const int tid = threadIdx.x, w = tid >> 6, lane = tid & 63;
  const int b = blockIdx.x;
  if (tid < 32) { lcnt[tid] = 0; lcsum[tid] = 0.f; }
  if (tid == 0) lpres = 0u;
  // (no barrier: lcnt/lcsum/lpres are produced & consumed by wave 0 only)

  float4 ca = {0.f, 0.f, 0.f, 0.f}, cb = {0.f, 0.f, 0.f, 0.f};
  float wssq = 0.f;
  #pragma unroll
  for (int r = 0; r < 2; ++r) {            // 2 rows per wave, 8 rows per block
    const int row = b * 8 + r * 4 + w;
    const float* p = (row < B) ? src + (size_t)row * D : tgt + (size_t)(row - B) * D;
    float4 a  = ((const float4*)p)[lane];        // cols lane*4 .. +4
    float4 bb = ((const float4*)p)[lane + 64];   // cols 256+lane*4 .. +4
    ushort4 ha, hb;
    ha.x = f2bf(a.x); ha.y = f2bf(a.y); ha.z = f2bf(a.z); ha.w = f2bf(a.w);
    hb.x = f2bf(bb.x); hb.y = f2bf(bb.y); hb.z = f2bf(bb.z); hb.w = f2bf(bb.w);
    size_t rb8 = (size_t)row * 512;
    *(ushort4*)(Xc + rb8 + lane * 4)       = ha;
    *(ushort4*)(Xc + rb8 + 256 + lane * 4) = hb;
    float s = a.x*a.x + a.y*a.y + a.z*a.z + a.w*a.w
            + bb.x*bb.x + bb.y*bb.y + bb.z*bb.z + bb.w*bb.w;
    ca.x += a.x;  ca.y += a.y;  ca.z += a.z;  ca.w += a.w;
    cb.x += bb.x; cb.y += bb.y; cb.z += bb.z; cb.w += bb.w;
    #pragma unroll
    for (int off = 32; off; off >>= 1) s += __shfl_down(s, off);
    if (lane == 0) { wsf[WS_SQ + row] = s; wssq += s; }
  }

  // class stats for this block's 8 rows (wave 0 only; same-wave ordering)
  {
    const int r0 = b * 8;
    if (r0 < B) {
      if (tid < 8) atomicAdd(&lcnt[label[r0 + tid]], 1);
      if (tid < NCLS && lcnt[tid]) atomicAdd((int*)&wsf[WS_HIST] + tid, lcnt[tid]);
    } else {
      if (tid < 8) {
        const float* lp = logits + (size_t)(r0 - B + tid) * NCLS;
        float mx = -1e30f; int am = 0;
        #pragma unroll
        for (int c = 0; c < NCLS; c++) {
          float v = lp[c];
          atomicAdd(&lcsum[c], v);
          if (v > mx) { mx = v; am = c; }  // strict >: first max, matches argmax
        }
        atomicOr(&lpres, 1u << am);
      }
      if (tid < NCLS) atomicAdd(&wsf[WS_CSUM + tid], lcsum[tid]);
      if (tid == 0) atomicOr((unsigned*)&wsf[WS_PRES], lpres);
    }
  }

  // cross-wave column reduce (one barrier) + block sumsq via red_
  *(float4*)&colbuf[w][lane * 4]       = ca;   // dense float4: conflict-free
  *(float4*)&colbuf[w][256 + lane * 4] = cb;
  if (lane == 0) red_[w] = wssq;
  __syncthreads();
  {
    float c0 = colbuf[0][tid] + colbuf[1][tid] + colbuf[2][tid] + colbuf[3][tid];
    float c1 = colbuf[0][tid+256] + colbuf[1][tid+256] + colbuf[2][tid+256] + colbuf[3][tid+256];
    const int bkt = (b & 7) * 512;
    atomicAdd(&wsf[WS_COLP + bkt + tid], c0);
    atomicAdd(&wsf[WS_COLP + bkt + 256 + tid], c1);
    if (tid == 0)
      atomicAdd(&wsf[WS_SUMSQB + (b & 7)], red_[0] + red_[1] + red_[2] + red_[3]);
  }

  // done-counter; last block finalizes stats
  __syncthreads();
  if (tid == 0)
    lastblk = (__hip_atomic_fetch_add((int*)&wsf[WS_CNT2], 1,
               __ATOMIC_RELEASE, __HIP_MEMORY_SCOPE_AGENT) == NPRE - 1);
  __syncthreads();
  if (!lastblk) return;
  __threadfence();  // acquire: see all blocks' atomics/stores
  float cs0 = 0.f, cs1 = 0.f;
  #pragma unroll
  for (int bk = 0; bk < 8; bk++) {
    cs0 += wsf[WS_COLP + bk * 512 + tid];
    cs1 += wsf[WS_COLP + bk * 512 + 256 + tid];
  }
  float v = cs0 * cs0 + cs1 * cs1;
  #pragma unroll
  for (int off = 32; off; off >>= 1) v += __shfl_down(v, off);
  if (lane == 0) red_[w] = v;
  __syncthreads();
  if (tid < 32) {
    // one class per lane (parallel loads), ballot for the mask count
    unsigned presT = *(unsigned*)&wsf[WS_PRES];
    const int c = tid;
    int cnt = (c < NCLS) ? ((int*)&wsf[WS_HIST])[c] : 0;
    float csum = (c < NCLS) ? wsf[WS_CSUM + c] : 0.f;
    bool m = (cnt > 0) && ((presT >> c) & 1u);
    if (csum == 0.f) csum = 100.f;
    wsf[WS_SVAL + c] = m ? 1.f / (float)cnt : 0.f;
    wsf[WS_TVAL + c] = m ? -1.f / csum : 0.f;
    unsigned long long bal = __ballot(m);
    if (tid == 0) {
      int cm = __popcll(bal);
      float scale = (cm > 0) ? 1.f / (float)cm : 0.f;
      float pp = (float)iter_p[0] / 1000.f;
      float lamb = 2.f / (1.f + __expf(-pp)) - 1.f;
      wsf[WS_SL] = scale * lamb;
      double colnorm2 = (double)red_[0] + red_[1] + red_[2] + red_[3];
      double sumsq = 0.0;
      for (int bk = 0; bk < 8; bk++) sumsq += (double)wsf[WS_SUMSQB + bk];
      double sumL2 = 2.0 * (double)N * sumsq - 2.0 * colnorm2;
      wsf[WS_NBT] = (float)(-((double)N * (double)N - (double)N) / (4.0 * sumL2));
    }
  }
}

// k_main: R1 version verbatim (95 µs, VGPR 84, no spills). Triple-buffered
// staging + counted vmcnt(4); R2/R3 structure gambles both lost to VGPR
// pressure (scratch WRITE_SIZE 10.8/86 MB) — this shape is the validated one.
__launch_bounds__(256, 3)
__global__ void k_main(const unsigned short* __restrict__ Xc,
                       const int* __restrict__ label, const float* __restrict__ logits,
                       float* __restrict__ wsf, float* __restrict__ out) {
  __shared__ __align__(16) short tA[3][BT * BK32];   // 3 x 8 KB
  __shared__ __align__(16) short tB[3][BT * BK32];   // 3 x 8 KB
  __shared__ float sqi[BT], sqj[BT];
  __shared__ float red[4];

  // triangular block decode: bi <= bj, S(bi) = bi*(129-bi)/2
  int bid = blockIdx.x;
  int bi = (int)(64.5f - sqrtf(64.5f * 64.5f - 2.0f * (float)bid));
  while (bi > 0 && bid < (bi * (129 - bi)) / 2) --bi;
  while (bid >= ((bi + 1) * (128 - bi)) / 2) ++bi;
  int bj = bi + (bid - (bi * (129 - bi)) / 2);
  const int i0 = bi * BT, j0 = bj * BT;
  const float mult = (bi == bj) ? 1.f : 2.f;

  const int tid = threadIdx.x;
  const int w = tid >> 6, lane = tid & 63;
  const int woff_m = (w >> 1) * 64, woff_n = (w & 1) * 64;
  const int fr = lane & 15, fg = lane >> 4;       // fragment row / k-group
  // staging: each inst covers 16 rows x 64 B; lane -> (r_local, swizzled granule)
  const int s_r  = lane >> 2;                     // r_local 0..15
  const int s_g  = (lane & 3) ^ ((s_r >> 1) & 3); // logical granule (inverts swizzle)

  // issue staging for iteration `it` (K-offset it*32) into buffer `bf`
  #define ISSUE(it, bf) do {                                                   \
    const int off = (it) * 32;                                                 \
    _Pragma("unroll")                                                          \
    for (int q = 0; q < 2; ++q) {                                              \
      const int inst = w * 2 + q;              /* 0..7, 16 rows each */        \
      const int rl = inst * 16 + s_r;                                          \
      async_lds16(Xc + (size_t)(i0 + rl) * 512 + off + s_g * 8,                \
                  &tA[bf][inst * 512]);                                        \
      async_lds16(Xc + (size_t)(j0 + rl) * 512 + off + s_g * 8,                \
                  &tB[bf][inst * 512]);                                        \
    }                                                                          \
  } while (0)

  ISSUE(0, 0);
  ISSUE(1, 1);

  if (tid < 128) sqi[tid] = wsf[WS_SQ + i0 + tid];
  else           sqj[tid - 128] = wsf[WS_SQ + j0 + (tid - 128)];
  const float nbt = wsf[WS_NBT];

  f32x4 acc[4][4];
  #pragma unroll
  for (int mt = 0; mt < 4; mt++)
    #pragma unroll
    for (int nt = 0; nt < 4; nt++) acc[mt][nt] = (f32x4){0.f, 0.f, 0.f, 0.f};

  __syncthreads();  // full drain: buf0/buf1 staged, sq/nbt loads retired (vmcnt=0)

  #pragma unroll
  for (int it = 0; it < NITER; ++it) {
    // outstanding at top of it: {ISSUE(it), ISSUE(it+1)} (8) for it>=2;
    // it in {0,1}: data already drained by the prologue __syncthreads.
    if (it >= 1) {
      if (it >= 2 && it < NITER - 1)
        asm volatile("s_waitcnt vmcnt(4)" ::: "memory");
      if (it == NITER - 1)
        asm volatile("s_waitcnt vmcnt(0)" ::: "memory");
      __builtin_amdgcn_s_barrier();
      __builtin_amdgcn_sched_barrier(0);
    }
    const int cur = it % 3;
    bf16x8 af[4], bfr[4];
    #pragma unroll
    for (int mt = 0; mt < 4; mt++)
      af[mt] = frag32(tA[cur], woff_m + mt * 16 + fr, fg);
    #pragma unroll
    for (int nt = 0; nt < 4; nt++)
      bfr[nt] = frag32(tB[cur], woff_n + nt * 16 + fr, fg);
    // overwrite the buffer consumed at it-1: (it+2)%3 == (it-1)%3; all waves'
    // reads of it retired before they crossed this iteration's barrier.
    if (it + 2 < NITER) ISSUE(it + 2, (it + 2) % 3);
    #pragma unroll
    for (int mt = 0; mt < 4; mt++)
      #pragma unroll
      for (int nt = 0; nt < 4; nt++)
        acc[mt][nt] = __builtin_amdgcn_mfma_f32_16x16x32_bf16(
            af[mt], bfr[nt], acc[mt][nt], 0, 0, 0);
  }

  // acc -> multi-band Gaussian kernel: t + t^2 + t^4 + t^8 + t^16
  float sj4[4], si16[4][4];
  #pragma unroll
  for (int nt = 0; nt < 4; nt++) sj4[nt] = sqj[woff_n + nt * 16 + fr];
  #pragma unroll
  for (int mt = 0; mt < 4; mt++)
    #pragma unroll
    for (int t = 0; t < 4; t++) si16[mt][t] = sqi[woff_m + mt * 16 + fg * 4 + t];
  #pragma unroll
  for (int mt = 0; mt < 4; mt++)
    #pragma unroll
    for (int nt = 0; nt < 4; nt++)
      #pragma unroll
      for (int t = 0; t < 4; t++) {
        float d2 = fmaxf(si16[mt][t] + sj4[nt] - 2.f * acc[mt][nt][t], 0.f);
        float e1 = __expf(d2 * nbt);
        float e2 = e1 * e1, e4 = e2 * e2, e8 = e4 * e4, e16 = e8 * e8;
        acc[mt][nt][t] = ((e16 + e8) + (e4 + e2)) + e1;
      }

  // build Q tiles: Qi-hi->tA[0], Qi-lo->tA[1], Qj-hi->tB[0], Qj-lo->tB[1]
  __syncthreads();
  {
    const int t = tid & 127;
    short* qh = (tid < 128) ? tA[0] : tB[0];
    short* ql = (tid < 128) ? tA[1] : tB[1];
    const int gq = ((tid < 128) ? i0 : j0) + t;
    const int lab = (gq < B) ? label[gq] : -1;
    const float sv = (gq < B) ? wsf[WS_SVAL + lab] : 0.f;
    const float* lp = (gq < B) ? (const float*)0 : logits + (size_t)(gq - B) * NCLS;
    #pragma unroll
    for (int g = 0; g < 4; ++g) {
      u16x8 ph = (u16x8){0,0,0,0,0,0,0,0}, pl = (u16x8){0,0,0,0,0,0,0,0};
      const int cbase = g * 8;
      if (gq < B) {
        if (lab >= cbase && lab < cbase + 8) {
          unsigned short h = f2bf(sv);
          ph[lab - cbase] = h;
          pl[lab - cbase] = f2bf(sv - bf2f(h));
        }
      } else {
        #pragma unroll
        for (int jc = 0; jc < 8; ++jc) {
          int cc = cbase + jc;
          if (cc < NCLS) {
            float vq = lp[cc] * wsf[WS_TVAL + cc];
            unsigned short h = f2bf(vq);
            ph[jc] = h;
            pl[jc] = f2bf(vq - bf2f(h));
          }
        }
      }
      int phys = (t * 4 + (g ^ ((t >> 1) & 3))) * 8;
      *(u16x8*)(qh + phys) = ph;
      *(u16x8*)(ql + phys) = pl;
    }
  }
  __syncthreads();

  // Gram via MFMA (K=96: hi.hi + lo.hi + hi.lo), elementwise-dot with kernel values
  float part = 0.f;
  #pragma unroll
  for (int ch = 0; ch < 3; ++ch) {
    const short* qa = (ch == 1) ? tA[1] : tA[0];
    const short* qb = (ch == 2) ? tB[1] : tB[0];
    bf16x8 af[4], bfr[4];
    #pragma unroll
    for (int mt = 0; mt < 4; mt++)
      af[mt] = frag32(qa, woff_m + mt * 16 + fr, fg);
    #pragma unroll
    for (int nt = 0; nt < 4; nt++)
      bfr[nt] = frag32(qb, woff_n + nt * 16 + fr, fg);
    #pragma unroll
    for (int mt = 0; mt < 4; mt++)
      #pragma unroll
      for (int nt = 0; nt < 4; nt++) {
        f32x4 z = (f32x4){0.f, 0.f, 0.f, 0.f};
        f32x4 g = __builtin_amdgcn_mfma_f32_16x16x32_bf16(af[mt], bfr[nt], z, 0, 0, 0);
        part += acc[mt][nt].x * g.x + acc[mt][nt].y * g.y
              + acc[mt][nt].z * g.z + acc[mt][nt].w * g.w;
      }
  }
  part *= mult;
  #pragma unroll
  for (int off = 32; off; off >>= 1) part += __shfl_down(part, off);
  if (lane == 0) red[w] = part;
  __syncthreads();

  // wave-0 finalize: bucketed atomic + release counter; last block sums & writes out
  if (w == 0) {
    float bs = red[0] + red[1] + red[2] + red[3];
    if (lane == 0) atomicAdd(&wsf[WS_ACCB + (blockIdx.x & 63) * 16], bs);
    int old = 0;
    if (lane == 0)
      old = __hip_atomic_fetch_add((int*)&wsf[WS_CNT], 1,
                                   __ATOMIC_RELEASE, __HIP_MEMORY_SCOPE_AGENT);
    old = __shfl(old, 0);
    if (old == NBLK - 1) {
      __builtin_amdgcn_fence(__ATOMIC_ACQUIRE, "agent");
      float t = __hip_atomic_load(&wsf[WS_ACCB + lane * 16],
                                  __ATOMIC_RELAXED, __HIP_MEMORY_SCOPE_AGENT);
      #pragma unroll
      for (int off = 32; off; off >>= 1) t += __shfl_down(t, off);
      if (lane == 0) out[0] = t * wsf[WS_SL];
    }
  }
}

extern "C" void kernel_launch(void* const* d_in, const int* in_sizes, int n_in,
                              void* d_out, int out_size, void* d_ws, size_t ws_size,
                              hipStream_t stream) {
  const float* src    = (const float*)d_in[0];
  const float* tgt    = (const float*)d_in[1];
  const int*   label  = (const int*)d_in[2];
  const float* logits = (const float*)d_in[3];
  const int*   iter_p = (const int*)d_in[4];
  float* wsf = (float*)d_ws;
  unsigned short* Xc = (unsigned short*)((char*)d_ws + WS_XC_BYTES);
  float* out = (float*)d_out;

  hipMemsetAsync(d_ws, 0, 24576, stream);   // zero scalars/counters/buckets/stats
  k_pre<<<NPRE, 256, 0, stream>>>(src, tgt, label, logits, iter_p, wsf, Xc);
  k_main<<<NBLK, 256, 0, stream>>>(Xc, label, logits, wsf, out);
}